// Round 3
// baseline (311.225 us; speedup 1.0000x reference)
//
#include <hip/hip_runtime.h>
#include <math.h>

#define IMG_H 96
#define IMG_W 96
#define HW (IMG_H * IMG_W)
#define RS 37   // tile row stride: 36 cols + 1 pad (2-way LDS bank alias = free)

// ---- build u_hat[32] for one (t, o) from conv raw outputs (bias pre-added) --
__device__ __forceinline__ void emit_uh(const float* rp, const float* ra,
                                        int o, int t, int w, int h,
                                        const float* __restrict__ Wp,
                                        const float* __restrict__ Wa,
                                        float* uh)
{
    float mn[16], ma[16];
    const float4* wp4 = (const float4*)(Wp + o * 128 + t * 16);
    const float4* wa4 = (const float4*)(Wa + o * 128 + t * 16);
    #pragma unroll
    for (int k = 0; k < 4; ++k) {
        float4 a = wp4[k];
        mn[4*k+0] = a.x; mn[4*k+1] = a.y; mn[4*k+2] = a.z; mn[4*k+3] = a.w;
        float4 b = wa4[k];
        ma[4*k+0] = b.x; ma[4*k+1] = b.y; ma[4*k+2] = b.z; ma[4*k+3] = b.w;
    }
    #pragma unroll
    for (int c = 0; c < 4; ++c) {   // column-normalize W_pos (axis=-2)
        float s = mn[c]*mn[c] + mn[4+c]*mn[4+c] + mn[8+c]*mn[8+c] + mn[12+c]*mn[12+c];
        float inv = 1.0f / sqrtf(fmaxf(s, 1e-12f));
        mn[c] *= inv; mn[4+c] *= inv; mn[8+c] *= inv; mn[12+c] *= inv;
    }
    mn[12] += (float)w * (1.0f / 96.0f);   // coord add [row3,col0] += x/W
    mn[13] += (float)h * (1.0f / 96.0f);   // [row3,col1] += y/H
    #pragma unroll
    for (int p0 = 0; p0 < 4; ++p0) {
        #pragma unroll
        for (int c = 0; c < 4; ++c) {
            uh[p0*4+c]    = rp[p0*4+0]*mn[c]   + rp[p0*4+1]*mn[4+c]
                          + rp[p0*4+2]*mn[8+c] + rp[p0*4+3]*mn[12+c];
            uh[16+p0*4+c] = ra[p0*4+0]*ma[c]   + ra[p0*4+1]*ma[4+c]
                          + ra[p0*4+2]*ma[8+c] + ra[p0*4+3]*ma[12+c];
        }
    }
}

// ---- 3-iter dynamic routing for one capsule; o summed via shfl over lane
//      bits [1:0]; last iter writes 8 z-planes per lane -------------------
__device__ __forceinline__ void route_store(const float* uh, int o, int nt,
                                            int pix, float* __restrict__ out)
{
    float bl = 0.0f;
    #pragma unroll
    for (int it = 0; it < 3; ++it) {
        float r = 1.0f / (1.0f + __expf(-bl));
        float p[32];
        #pragma unroll
        for (int z = 0; z < 32; ++z) {
            float c = uh[z] * r;
            c += __shfl_xor(c, 1);
            c += __shfl_xor(c, 2);
            p[z] = c;                      // p replicated across the 4 o-lanes
        }
        float mx = 0.0f, n2 = 0.0f;
        #pragma unroll
        for (int z = 0; z < 16; ++z) mx = fmaxf(mx, fabsf(p[z]));
        #pragma unroll
        for (int z = 16; z < 32; ++z) n2 = fmaf(p[z], p[z], n2);
        float invm = 1.0f / mx;                          // psquash (no eps, as ref)
        float sc   = n2 / ((1.0f + n2) * sqrtf(n2 + 1e-9f));  // matwo squash
        if (it < 2) {
            float dp = 0.0f, da = 0.0f;
            #pragma unroll
            for (int z = 0; z < 16; ++z)  dp = fmaf(uh[z], p[z], dp);
            #pragma unroll
            for (int z = 16; z < 32; ++z) da = fmaf(uh[z], p[z], da);
            bl += (invm * dp) * (sc * da);
        } else {
            float scale = (o < 2) ? invm : sc;
            float* op = out + ((size_t)nt * 32 + o * 8) * HW + pix;
            #pragma unroll
            for (int j = 0; j < 8; ++j) {   // select p[o*8+j] w/o dynamic indexing
                float lo = (o & 1) ? p[8+j]  : p[j];
                float hi = (o & 1) ? p[24+j] : p[16+j];
                float v  = (o & 2) ? hi : lo;
                op[(size_t)j * HW] = v * scale;
            }
        }
    }
}

// Block 256 = 32 px * 4 o * 2 tsub. Grid (3 wtiles, 96 h, 4 n).
// Per parity (z-half): stage tile, conv 2 capsule types/thread (4 FMA/read),
// emit u_hat in regs, route + store immediately. No workspace.
__global__ __launch_bounds__(256, 3)
void caps_one_kernel(const float* __restrict__ x,    // (4,4,32,96,96)
                     const float* __restrict__ Wc,   // (4,5,5,1,8)
                     const float* __restrict__ Wp,   // (4,16,8)
                     const float* __restrict__ Wa,   // (4,16,8)
                     const float* __restrict__ Ba,   // (4,8)
                     float* __restrict__ out)        // (4,8,32,96,96)
{
    __shared__ float tile[320 * RS];   // [(dy*64 + o*16 + zq)][m], m = w-(wb-2)
    __shared__ float wsh[800];         // conv weights [o][k25][f8]

    const int tid  = threadIdx.x;
    const int o    = tid & 3;
    const int px   = (tid >> 2) & 31;
    const int tsub = tid >> 7;
    const int wb   = blockIdx.x * 32;
    const int h    = blockIdx.y;
    const int n    = blockIdx.z;
    const int w    = wb + px;
    const int pix  = h * IMG_W + w;

    for (int i = tid; i < 800; i += 256) wsh[i] = Wc[i];

    #pragma unroll 1
    for (int parity = 0; parity < 2; ++parity) {
        __syncthreads();
        // ---- structured staging: all shifts/masks, no divides ----
        {
            const int chanbase = n * 128 + parity * 16;
            const int rowsel = tid >> 5;          // 0..7
            const int col    = tid & 31;
            #pragma unroll
            for (int k = 0; k < 40; ++k) {
                int r  = rowsel + (k << 3);       // 0..319 = (dy*64 + c)
                int dy = r >> 6;
                int c  = r & 63;
                int hh = h + dy - 2;
                int chan = chanbase + c + (c & 48);   // = n*128 + oi*32 + par*16 + zq
                float v = 0.0f;
                if ((unsigned)hh < IMG_H)
                    v = x[(size_t)chan * HW + hh * IMG_W + wb + col];
                tile[r * RS + 2 + col] = v;
            }
            const int hc = tid & 3;
            const int m  = (hc < 2) ? hc : hc + 32;   // cols 0,1,34,35
            const int ww = wb - 2 + m;
            const int rh = tid >> 2;                  // 0..63
            #pragma unroll
            for (int k = 0; k < 5; ++k) {
                int r  = rh + (k << 6);
                int dy = r >> 6;
                int c  = r & 63;
                int hh = h + dy - 2;
                int chan = chanbase + c + (c & 48);
                float v = 0.0f;
                if ((unsigned)hh < IMG_H && (unsigned)ww < IMG_W)
                    v = x[(size_t)chan * HW + hh * IMG_W + ww];
                tile[r * RS + m] = v;
            }
        }
        __syncthreads();

        // ---- conv 5x5: 2 capsule types (t_a, t_b) per thread ----
        float rpa[16], rpb[16], raa[16], rab[16];
        #pragma unroll
        for (int q = 0; q < 16; ++q) { rpa[q]=0.f; rpb[q]=0.f; raa[q]=0.f; rab[q]=0.f; }

        #pragma unroll
        for (int dy = 0; dy < 5; ++dy) {
            const float* trow = &tile[(dy * 64 + o * 16) * RS + px];
            const float* wrow = &wsh[o * 200 + dy * 40 + (tsub << 1)];
            #pragma unroll
            for (int dx = 0; dx < 5; ++dx) {
                float2 wpv = *(const float2*)(wrow + dx * 8);      // pos filt a,b
                float2 wav = *(const float2*)(wrow + dx * 8 + 4);  // app filt a,b
                #pragma unroll
                for (int q = 0; q < 16; ++q) {
                    float v = trow[q * RS + dx];
                    rpa[q] = fmaf(v, wpv.x, rpa[q]);
                    rpb[q] = fmaf(v, wpv.y, rpb[q]);
                    raa[q] = fmaf(v, wav.x, raa[q]);
                    rab[q] = fmaf(v, wav.y, rab[q]);
                }
            }
        }

        const int t_a = parity + 4 * tsub;
        const int t_b = t_a + 2;
        const float ba_a = Ba[o * 8 + t_a];
        const float ba_b = Ba[o * 8 + t_b];
        #pragma unroll
        for (int q = 0; q < 16; ++q) { raa[q] += ba_a; rab[q] += ba_b; }

        float uhA[32], uhB[32];
        emit_uh(rpa, raa, o, t_a, w, h, Wp, Wa, uhA);
        emit_uh(rpb, rab, o, t_b, w, h, Wp, Wa, uhB);

        route_store(uhA, o, n * 8 + t_a, pix, out);
        route_store(uhB, o, n * 8 + t_b, pix, out);
    }
}

extern "C" void kernel_launch(void* const* d_in, const int* in_sizes, int n_in,
                              void* d_out, int out_size, void* d_ws, size_t ws_size,
                              hipStream_t stream) {
    const float* x  = (const float*)d_in[0];
    const float* Wc = (const float*)d_in[1];
    const float* Wp = (const float*)d_in[2];
    const float* Wa = (const float*)d_in[3];
    const float* Ba = (const float*)d_in[4];
    float* outp = (float*)d_out;

    caps_one_kernel<<<dim3(3, 96, 4), 256, 0, stream>>>(x, Wc, Wp, Wa, Ba, outp);
}

// Round 4
// 185.498 us; speedup vs baseline: 1.6778x; 1.6778x over previous
//
#include <hip/hip_runtime.h>
#include <math.h>

#define IMG_H 96
#define IMG_W 96
#define HW (IMG_H * IMG_W)
#define XS 68   // LDS dword stride per x-column: 64 chans + 4 pad
                // bank-quad = (17*x + 4*o) mod 8 -> uniform 8 lanes/quad (b128 floor)

// sum over the 4 o-lanes of a quad (o = tid&3) via DPP quad_perm butterflies
__device__ __forceinline__ float quad_sum(float v) {
    v += __int_as_float(__builtin_amdgcn_update_dpp(
            0, __float_as_int(v), 0xB1, 0xF, 0xF, true));   // quad_perm [1,0,3,2]
    v += __int_as_float(__builtin_amdgcn_update_dpp(
            0, __float_as_int(v), 0x4E, 0xF, 0xF, true));   // quad_perm [2,3,0,1]
    return v;
}

// ---- build u_hat[32] for one (t, o) from conv raw outputs (bias pre-added) --
__device__ __forceinline__ void emit_uh(const float* rp, const float* ra,
                                        int o, int t, int w, int h,
                                        const float* __restrict__ Wp,
                                        const float* __restrict__ Wa,
                                        float* uh)
{
    float mn[16], ma[16];
    const float4* wp4 = (const float4*)(Wp + o * 128 + t * 16);
    const float4* wa4 = (const float4*)(Wa + o * 128 + t * 16);
    #pragma unroll
    for (int k = 0; k < 4; ++k) {
        float4 a = wp4[k];
        mn[4*k+0] = a.x; mn[4*k+1] = a.y; mn[4*k+2] = a.z; mn[4*k+3] = a.w;
        float4 b = wa4[k];
        ma[4*k+0] = b.x; ma[4*k+1] = b.y; ma[4*k+2] = b.z; ma[4*k+3] = b.w;
    }
    #pragma unroll
    for (int c = 0; c < 4; ++c) {   // column-normalize W_pos (axis=-2)
        float s = mn[c]*mn[c] + mn[4+c]*mn[4+c] + mn[8+c]*mn[8+c] + mn[12+c]*mn[12+c];
        float inv = 1.0f / sqrtf(fmaxf(s, 1e-12f));
        mn[c] *= inv; mn[4+c] *= inv; mn[8+c] *= inv; mn[12+c] *= inv;
    }
    mn[12] += (float)w * (1.0f / 96.0f);   // coord add [row3,col0] += x/W
    mn[13] += (float)h * (1.0f / 96.0f);   // [row3,col1] += y/H
    #pragma unroll
    for (int p0 = 0; p0 < 4; ++p0) {
        #pragma unroll
        for (int c = 0; c < 4; ++c) {
            uh[p0*4+c]    = rp[p0*4+0]*mn[c]   + rp[p0*4+1]*mn[4+c]
                          + rp[p0*4+2]*mn[8+c] + rp[p0*4+3]*mn[12+c];
            uh[16+p0*4+c] = ra[p0*4+0]*ma[c]   + ra[p0*4+1]*ma[4+c]
                          + ra[p0*4+2]*ma[8+c] + ra[p0*4+3]*ma[12+c];
        }
    }
}

// ---- 3-iter routing for one capsule; o summed across quad lanes -----------
__device__ __forceinline__ void route_store(const float* uh, int o, int nt,
                                            int pix, float* __restrict__ out)
{
    float bl = 0.0f;
    #pragma unroll
    for (int it = 0; it < 2; ++it) {       // two update iterations (single pass)
        float r = 1.0f / (1.0f + __expf(-bl));
        float mx = 0.0f, n2 = 0.0f, dp = 0.0f, da = 0.0f;
        #pragma unroll
        for (int z = 0; z < 16; ++z) {
            float p = quad_sum(uh[z] * r);
            mx = fmaxf(mx, fabsf(p));
            dp = fmaf(uh[z], p, dp);
        }
        #pragma unroll
        for (int z = 16; z < 32; ++z) {
            float p = quad_sum(uh[z] * r);
            n2 = fmaf(p, p, n2);
            da = fmaf(uh[z], p, da);
        }
        float invm = 1.0f / mx;                               // psquash
        float sc   = n2 / ((1.0f + n2) * sqrtf(n2 + 1e-9f));  // matwo squash
        bl += (invm * dp) * (sc * da);
    }
    // final iteration: need p values for the store
    float r = 1.0f / (1.0f + __expf(-bl));
    float p[32];
    float mx = 0.0f, n2 = 0.0f;
    #pragma unroll
    for (int z = 0; z < 16; ++z) {
        p[z] = quad_sum(uh[z] * r);
        mx = fmaxf(mx, fabsf(p[z]));
    }
    #pragma unroll
    for (int z = 16; z < 32; ++z) {
        p[z] = quad_sum(uh[z] * r);
        n2 = fmaf(p[z], p[z], n2);
    }
    float invm = 1.0f / mx;
    float sc   = n2 / ((1.0f + n2) * sqrtf(n2 + 1e-9f));
    float scale = (o < 2) ? invm : sc;
    float* op = out + ((size_t)nt * 32 + o * 8) * HW + pix;
    #pragma unroll
    for (int j = 0; j < 8; ++j) {          // select p[o*8+j] w/o dynamic indexing
        float lo = (o & 1) ? p[8+j]  : p[j];
        float hi = (o & 1) ? p[24+j] : p[16+j];
        float v  = (o & 2) ? hi : lo;
        op[(size_t)j * HW] = v * scale;
    }
}

// Block 256 = 32 px * 4 o * 2 tsub. Grid (3 wtiles, 96 h, 4 n).
__global__ __launch_bounds__(256, 3)
void caps_one_kernel(const float* __restrict__ x,    // (4,4,32,96,96)
                     const float* __restrict__ Wc,   // (4,5,5,1,8)
                     const float* __restrict__ Wp,   // (4,16,8)
                     const float* __restrict__ Wa,   // (4,16,8)
                     const float* __restrict__ Ba,   // (4,8)
                     float* __restrict__ out)        // (4,8,32,96,96)
{
    __shared__ float tile[5 * 36 * XS];   // [dy][x][chan 64 (+4 pad)]  48.96 KB
    __shared__ float wsh[800];            // conv weights [o][k25][f8]

    const int tid  = threadIdx.x;
    const int o    = tid & 3;
    const int px   = (tid >> 2) & 31;
    const int tsub = tid >> 7;
    const int wb   = blockIdx.x * 32;
    const int h    = blockIdx.y;
    const int n    = blockIdx.z;
    const int w    = wb + px;
    const int pix  = h * IMG_W + w;

    for (int i = tid; i < 800; i += 256) wsh[i] = Wc[i];

    #pragma unroll 1
    for (int parity = 0; parity < 2; ++parity) {
        __syncthreads();
        // ---- staging: interior 32 cols (coalesced 128B rows) ----
        {
            const int col = tid & 31;
            const int r0  = tid >> 5;
            #pragma unroll 8
            for (int k = 0; k < 40; ++k) {
                int r  = r0 + (k << 3);          // r = dy*64 + c, 0..319
                int dy = r >> 6;
                int c  = r & 63;
                int hh = h + dy - 2;
                int chan = n * 128 + ((c >> 4) << 5) + (parity << 4) + (c & 15);
                float v = 0.0f;
                if ((unsigned)hh < IMG_H)
                    v = x[(size_t)chan * HW + hh * IMG_W + wb + col];
                tile[(dy * 36 + 2 + col) * XS + c] = v;
            }
            // halo: x in {0,1,34,35}
            const int m  = tid & 3;
            const int xx = (m < 2) ? m : (m + 32);
            const int ww = wb - 2 + xx;
            const int r1 = tid >> 2;
            #pragma unroll 5
            for (int k = 0; k < 5; ++k) {
                int r  = r1 + (k << 6);
                int dy = r >> 6;
                int c  = r & 63;
                int hh = h + dy - 2;
                int chan = n * 128 + ((c >> 4) << 5) + (parity << 4) + (c & 15);
                float v = 0.0f;
                if ((unsigned)hh < IMG_H && (unsigned)ww < IMG_W)
                    v = x[(size_t)chan * HW + hh * IMG_W + ww];
                tile[(dy * 36 + xx) * XS + c] = v;
            }
        }
        __syncthreads();

        // ---- conv 5x5: 2 capsule types per thread, 16 q via 4x ds_read_b128
        float rpa[16], rpb[16], raa[16], rab[16];
        #pragma unroll
        for (int q = 0; q < 16; ++q) { rpa[q]=0.f; rpb[q]=0.f; raa[q]=0.f; rab[q]=0.f; }

        const float* wbase = &wsh[o * 200 + (tsub << 1)];
        #pragma unroll 1
        for (int dy = 0; dy < 5; ++dy) {
            #pragma unroll
            for (int dx = 0; dx < 5; ++dx) {
                const float4* t4 =
                    (const float4*)&tile[(dy * 36 + px + dx) * XS + (o << 4)];
                float4 q0 = t4[0], q1 = t4[1], q2 = t4[2], q3 = t4[3];
                const float* wr = wbase + dy * 40 + dx * 8;
                float wpa = wr[0], wpb = wr[1], waa = wr[4], wab = wr[5];
                float qq[16] = {q0.x,q0.y,q0.z,q0.w, q1.x,q1.y,q1.z,q1.w,
                                q2.x,q2.y,q2.z,q2.w, q3.x,q3.y,q3.z,q3.w};
                #pragma unroll
                for (int q = 0; q < 16; ++q) {
                    rpa[q] = fmaf(qq[q], wpa, rpa[q]);
                    rpb[q] = fmaf(qq[q], wpb, rpb[q]);
                    raa[q] = fmaf(qq[q], waa, raa[q]);
                    rab[q] = fmaf(qq[q], wab, rab[q]);
                }
            }
        }

        const int t_a = parity + 4 * tsub;
        const int t_b = t_a + 2;

        {   // capsule t_a first: rpa/raa die before t_b's emit
            const float ba_a = Ba[o * 8 + t_a];
            #pragma unroll
            for (int q = 0; q < 16; ++q) raa[q] += ba_a;
            float uhA[32];
            emit_uh(rpa, raa, o, t_a, w, h, Wp, Wa, uhA);
            route_store(uhA, o, n * 8 + t_a, pix, out);
        }
        {
            const float ba_b = Ba[o * 8 + t_b];
            #pragma unroll
            for (int q = 0; q < 16; ++q) rab[q] += ba_b;
            float uhB[32];
            emit_uh(rpb, rab, o, t_b, w, h, Wp, Wa, uhB);
            route_store(uhB, o, n * 8 + t_b, pix, out);
        }
    }
}

extern "C" void kernel_launch(void* const* d_in, const int* in_sizes, int n_in,
                              void* d_out, int out_size, void* d_ws, size_t ws_size,
                              hipStream_t stream) {
    const float* x  = (const float*)d_in[0];
    const float* Wc = (const float*)d_in[1];
    const float* Wp = (const float*)d_in[2];
    const float* Wa = (const float*)d_in[3];
    const float* Ba = (const float*)d_in[4];
    float* outp = (float*)d_out;

    caps_one_kernel<<<dim3(3, 96, 4), 256, 0, stream>>>(x, Wc, Wp, Wa, Ba, outp);
}